// Round 1
// baseline (2842.360 us; speedup 1.0000x reference)
//
#include <hip/hip_runtime.h>
#include <math.h>

#define BS   2048
#define DIM  2048
#define NE   64
#define NF   512
#define TOPK 8

// ---------------- zero out + counters ----------------
__global__ __launch_bounds__(256) void zero_kernel(float* __restrict__ out, int* __restrict__ count)
{
    const size_t idx = (size_t)blockIdx.x * blockDim.x + threadIdx.x;
    const size_t tot = (size_t)BS * DIM;
    for (size_t i = idx * 4; i < tot; i += (size_t)gridDim.x * blockDim.x * 4) {
        *(float4*)&out[i] = make_float4(0.f, 0.f, 0.f, 0.f);
    }
    if (idx < NE) count[idx] = 0;
}

// ---------------- router: logits -> mask -> top8 -> expert lists ----------------
__global__ __launch_bounds__(256) void router_kernel(
    const float* __restrict__ x, const float* __restrict__ gate_w,
    const int* __restrict__ token_mod, const int* __restrict__ expert_mod,
    int* __restrict__ count, int* __restrict__ list_token, float* __restrict__ list_w)
{
    __shared__ float xs[DIM];
    __shared__ float pr[NE];
    const int t   = blockIdx.x;
    const int tid = threadIdx.x;

    const float4* xrow = (const float4*)(x + (size_t)t * DIM);
    float4* xs4 = (float4*)xs;
    for (int i = tid; i < DIM / 4; i += 256) xs4[i] = xrow[i];
    __syncthreads();

    const int wave = tid >> 6, lane = tid & 63;
    const int tm = token_mod[t];
    for (int j = 0; j < 16; ++j) {
        const int e = wave * 16 + j;
        const float* w = gate_w + (size_t)e * DIM;
        float s = 0.f;
        for (int d = lane; d < DIM; d += 64) s += xs[d] * w[d];
        #pragma unroll
        for (int off = 32; off > 0; off >>= 1) s += __shfl_down(s, off, 64);
        if (lane == 0) {
            pr[e] = (tm * expert_mod[e] == -1) ? -INFINITY : s;
        }
    }
    __syncthreads();
    if (tid == 0) {
        // softmax denominator cancels under top-k renormalization; use exp(logit - max)
        float m = -INFINITY;
        for (int e2 = 0; e2 < NE; ++e2) m = fmaxf(m, pr[e2]);
        for (int e2 = 0; e2 < NE; ++e2) pr[e2] = __expf(pr[e2] - m);  // exp(-inf)=0
        int   sel[TOPK];
        float rw[TOPK];
        float s8 = 0.f;
        for (int k = 0; k < TOPK; ++k) {
            float best = -1.f; int bi = 0;
            for (int e2 = 0; e2 < NE; ++e2) {
                const float v = pr[e2];
                if (v > best) { best = v; bi = e2; }   // strict > == lowest index on ties (jax top_k)
            }
            sel[k] = bi; rw[k] = best; s8 += best;
            pr[bi] = -1.f;
        }
        const float inv = 1.f / s8;
        #pragma unroll
        for (int k = 0; k < TOPK; ++k) {
            const int e2  = sel[k];
            const int pos = atomicAdd(&count[e2], 1);
            list_token[e2 * BS + pos] = t;
            list_w[e2 * BS + pos]     = rw[k] * inv;
        }
    }
}

// ---------------- tiny exclusive scan over 64 counts ----------------
__global__ void scan_kernel(const int* __restrict__ count, int* __restrict__ offsets)
{
    if (threadIdx.x == 0) {
        int s = 0;
        for (int e = 0; e < NE; ++e) { offsets[e] = s; s += count[e]; }
    }
}

// ---------------- gate/up GEMM + SiLU, h[slot][512] = rw * silu(g) * u ----------------
#define TM1 64
#define TN1 64
#define KC1 32

__global__ __launch_bounds__(256) void gateup_kernel(
    const float* __restrict__ x,
    const float* __restrict__ w_gate, const float* __restrict__ w_up,
    const int* __restrict__ count, const int* __restrict__ offsets,
    const int* __restrict__ list_token, const float* __restrict__ list_w,
    float* __restrict__ h)
{
    const int e  = blockIdx.z;
    const int n  = count[e];
    const int m0 = blockIdx.y * TM1;
    if (m0 >= n) return;
    const int f0 = blockIdx.x * TN1;

    __shared__ float Xs[KC1][TM1 + 4];
    __shared__ float Gs[KC1][TN1 + 4];
    __shared__ float Us[KC1][TN1 + 4];
    __shared__ int   toks[TM1];

    const int tid = threadIdx.x;
    const int mc  = min(TM1, n - m0);
    if (tid < TM1) toks[tid] = list_token[e * BS + m0 + (tid < mc ? tid : 0)];
    __syncthreads();

    const float* wg = w_gate + (size_t)e * NF * DIM;
    const float* wu = w_up   + (size_t)e * NF * DIM;

    float accg[4][4] = {};
    float accu[4][4] = {};
    const int ty = tid >> 4;   // 16 groups -> 4 tokens each
    const int tx = tid & 15;   // 16 groups -> 4 f each

    for (int d0 = 0; d0 < DIM; d0 += KC1) {
        #pragma unroll
        for (int i = tid; i < TM1 * KC1; i += 256) {
            const int tok = i >> 5, kk = i & 31;
            Xs[kk][tok] = x[(size_t)toks[tok] * DIM + d0 + kk];
        }
        #pragma unroll
        for (int i = tid; i < TN1 * KC1; i += 256) {
            const int f = i >> 5, kk = i & 31;
            Gs[kk][f] = wg[(size_t)(f0 + f) * DIM + d0 + kk];
            Us[kk][f] = wu[(size_t)(f0 + f) * DIM + d0 + kk];
        }
        __syncthreads();
        #pragma unroll
        for (int kk = 0; kk < KC1; ++kk) {
            const float4 a  = *(const float4*)&Xs[kk][ty * 4];
            const float4 bg = *(const float4*)&Gs[kk][tx * 4];
            const float4 bu = *(const float4*)&Us[kk][tx * 4];
            const float av[4]  = {a.x, a.y, a.z, a.w};
            const float bgv[4] = {bg.x, bg.y, bg.z, bg.w};
            const float buv[4] = {bu.x, bu.y, bu.z, bu.w};
            #pragma unroll
            for (int r = 0; r < 4; ++r)
                #pragma unroll
                for (int c = 0; c < 4; ++c) {
                    accg[r][c] += av[r] * bgv[c];
                    accu[r][c] += av[r] * buv[c];
                }
        }
        __syncthreads();
    }

    const int base = offsets[e] + m0;
    #pragma unroll
    for (int r = 0; r < 4; ++r) {
        const int m = ty * 4 + r;
        if (m < mc) {
            const float wt = list_w[e * BS + m0 + m];
            float4 hv;
            float* o = (float*)&hv;
            #pragma unroll
            for (int c = 0; c < 4; ++c) {
                const float g = accg[r][c];
                const float u = accu[r][c];
                o[c] = wt * u * (g / (1.f + __expf(-g)));
            }
            *(float4*)&h[(size_t)(base + m) * NF + f0 + tx * 4] = hv;
        }
    }
}

// ---------------- down GEMM + atomic combine ----------------
#define TM2 64
#define TN2 64
#define FC2 32

__global__ __launch_bounds__(256) void down_kernel(
    const float* __restrict__ w_down,
    const int* __restrict__ count, const int* __restrict__ offsets,
    const int* __restrict__ list_token,
    const float* __restrict__ h, float* __restrict__ out)
{
    const int e  = blockIdx.z;
    const int n  = count[e];
    const int m0 = blockIdx.y * TM2;
    if (m0 >= n) return;
    const int d0 = blockIdx.x * TN2;

    __shared__ float Hs[FC2][TM2 + 4];
    __shared__ float Ws[FC2][TN2 + 4];
    __shared__ int   toks[TM2];

    const int tid = threadIdx.x;
    const int mc  = min(TM2, n - m0);
    if (tid < TM2) toks[tid] = list_token[e * BS + m0 + (tid < mc ? tid : 0)];
    __syncthreads();

    const float* wd  = w_down + (size_t)e * DIM * NF;
    const int   base = offsets[e] + m0;

    float acc[4][4] = {};
    const int ty = tid >> 4, tx = tid & 15;

    for (int fs = 0; fs < NF; fs += FC2) {
        #pragma unroll
        for (int i = tid; i < TM2 * FC2; i += 256) {
            const int m = i >> 5, ff = i & 31;
            Hs[ff][m] = h[(size_t)(base + (m < mc ? m : 0)) * NF + fs + ff];
        }
        #pragma unroll
        for (int i = tid; i < TN2 * FC2; i += 256) {
            const int dd = i >> 5, ff = i & 31;
            Ws[ff][dd] = wd[(size_t)(d0 + dd) * NF + fs + ff];
        }
        __syncthreads();
        #pragma unroll
        for (int ff = 0; ff < FC2; ++ff) {
            const float4 a = *(const float4*)&Hs[ff][ty * 4];
            const float4 b = *(const float4*)&Ws[ff][tx * 4];
            const float av[4] = {a.x, a.y, a.z, a.w};
            const float bv[4] = {b.x, b.y, b.z, b.w};
            #pragma unroll
            for (int r = 0; r < 4; ++r)
                #pragma unroll
                for (int c = 0; c < 4; ++c)
                    acc[r][c] += av[r] * bv[c];
        }
        __syncthreads();
    }

    #pragma unroll
    for (int r = 0; r < 4; ++r) {
        const int m = ty * 4 + r;
        if (m < mc) {
            const int t = toks[m];
            float* orow = out + (size_t)t * DIM + d0 + tx * 4;
            #pragma unroll
            for (int c = 0; c < 4; ++c) atomicAdd(&orow[c], acc[r][c]);
        }
    }
}

extern "C" void kernel_launch(void* const* d_in, const int* in_sizes, int n_in,
                              void* d_out, int out_size, void* d_ws, size_t ws_size,
                              hipStream_t stream)
{
    const float* x          = (const float*)d_in[0];
    const float* gate_w     = (const float*)d_in[1];
    const float* w_gate     = (const float*)d_in[2];
    const float* w_up       = (const float*)d_in[3];
    const float* w_down     = (const float*)d_in[4];
    const int*   token_mod  = (const int*)d_in[5];
    const int*   expert_mod = (const int*)d_in[6];
    float* out = (float*)d_out;

    // ws layout: h (16384*512 f32 = 33,554,432 B) | count (256 B) | offsets (256 B)
    //            | list_token (64*2048*4) | list_w (64*2048*4)   -> total ~34.6 MB
    char* ws = (char*)d_ws;
    float* h          = (float*)ws;
    int*   count      = (int*)(ws + 33554432);
    int*   offsets    = (int*)(ws + 33554432 + 256);
    int*   list_token = (int*)(ws + 33554432 + 512);
    float* list_w     = (float*)(ws + 33554432 + 512 + (size_t)NE * BS * 4);

    zero_kernel<<<2048, 256, 0, stream>>>(out, count);
    router_kernel<<<BS, 256, 0, stream>>>(x, gate_w, token_mod, expert_mod,
                                          count, list_token, list_w);
    scan_kernel<<<1, 64, 0, stream>>>(count, offsets);

    dim3 g1(NF / TN1, BS / TM1, NE);   // (8, 32, 64)
    gateup_kernel<<<g1, 256, 0, stream>>>(x, w_gate, w_up, count, offsets,
                                          list_token, list_w, h);
    dim3 g2(DIM / TN2, BS / TM2, NE);  // (32, 32, 64)
    down_kernel<<<g2, 256, 0, stream>>>(w_down, count, offsets, list_token, h, out);
}

// Round 2
// 1332.629 us; speedup vs baseline: 2.1329x; 2.1329x over previous
//
#include <hip/hip_runtime.h>
#include <math.h>

#define BS   2048
#define DIM  2048
#define NE   64
#define NF   512
#define TOPK 8

typedef __attribute__((ext_vector_type(8))) short bf16x8;
typedef __attribute__((ext_vector_type(4))) float f32x4;

__device__ __forceinline__ unsigned f2bf(float f) {
    union { float f; unsigned u; } v; v.f = f;
    return (v.u + 0x7FFF + ((v.u >> 16) & 1)) >> 16;   // RNE
}
__device__ __forceinline__ unsigned pack2(float a, float b) {
    return f2bf(a) | (f2bf(b) << 16);
}

// swizzled LDS addressing: 64-col bf16 rows (128 B), XOR bit4..6 with row&7
#define SWZ(r, b) (((((r) << 7) + (b)) ^ (((r) & 7) << 4)))

// ---------------- zero out + counters ----------------
__global__ __launch_bounds__(256) void zero_kernel(float* __restrict__ out, int* __restrict__ count)
{
    const size_t idx = (size_t)blockIdx.x * blockDim.x + threadIdx.x;
    const size_t tot = (size_t)BS * DIM;
    for (size_t i = idx * 4; i < tot; i += (size_t)gridDim.x * blockDim.x * 4) {
        *(float4*)&out[i] = make_float4(0.f, 0.f, 0.f, 0.f);
    }
    if (idx < NE) count[idx] = 0;
}

// ---------------- router: logits -> mask -> top8 -> expert lists ----------------
__global__ __launch_bounds__(256) void router_kernel(
    const float* __restrict__ x, const float* __restrict__ gate_w,
    const int* __restrict__ token_mod, const int* __restrict__ expert_mod,
    int* __restrict__ count, int* __restrict__ list_token, float* __restrict__ list_w)
{
    __shared__ float xs[DIM];
    __shared__ float pr[NE];
    const int t   = blockIdx.x;
    const int tid = threadIdx.x;

    const float4* xrow = (const float4*)(x + (size_t)t * DIM);
    float4* xs4 = (float4*)xs;
    for (int i = tid; i < DIM / 4; i += 256) xs4[i] = xrow[i];
    __syncthreads();

    const int wave = tid >> 6, lane = tid & 63;
    const int tm = token_mod[t];
    for (int j = 0; j < 16; ++j) {
        const int e = wave * 16 + j;
        const float* w = gate_w + (size_t)e * DIM;
        float s = 0.f;
        for (int d = lane; d < DIM; d += 64) s += xs[d] * w[d];
        #pragma unroll
        for (int off = 32; off > 0; off >>= 1) s += __shfl_down(s, off, 64);
        if (lane == 0) {
            pr[e] = (tm * expert_mod[e] == -1) ? -INFINITY : s;
        }
    }
    __syncthreads();
    if (tid == 0) {
        // softmax denominator cancels under top-k renormalization; use exp(logit - max)
        float m = -INFINITY;
        for (int e2 = 0; e2 < NE; ++e2) m = fmaxf(m, pr[e2]);
        for (int e2 = 0; e2 < NE; ++e2) pr[e2] = __expf(pr[e2] - m);  // exp(-inf)=0
        int   sel[TOPK];
        float rw[TOPK];
        float s8 = 0.f;
        for (int k = 0; k < TOPK; ++k) {
            float best = -1.f; int bi = 0;
            for (int e2 = 0; e2 < NE; ++e2) {
                const float v = pr[e2];
                if (v > best) { best = v; bi = e2; }
            }
            sel[k] = bi; rw[k] = best; s8 += best;
            pr[bi] = -1.f;
        }
        const float inv = 1.f / s8;
        #pragma unroll
        for (int k = 0; k < TOPK; ++k) {
            const int e2  = sel[k];
            const int pos = atomicAdd(&count[e2], 1);
            list_token[e2 * BS + pos] = t;
            list_w[e2 * BS + pos]     = rw[k] * inv;
        }
    }
}

// ---------------- tiny exclusive scan over 64 counts ----------------
__global__ void scan_kernel(const int* __restrict__ count, int* __restrict__ offsets)
{
    if (threadIdx.x == 0) {
        int s = 0;
        for (int e = 0; e < NE; ++e) { offsets[e] = s; s += count[e]; }
    }
}

// ---------------- gate/up MFMA GEMM + SiLU -> h (bf16) ----------------
// block: 128 tokens x 64 f, K-tile 64. 4 waves; wave = 64 tok x 32 f, gate+up.
#define GU_M 128
#define GU_F 64
#define GU_BK 64
#define XOFF 0
#define GOFF (128 * 128)          // 16 KB
#define UOFF (GOFF + 64 * 128)    // 24 KB

__global__ __launch_bounds__(256, 3) void gateup_mfma(
    const float* __restrict__ x,
    const float* __restrict__ w_gate, const float* __restrict__ w_up,
    const int* __restrict__ count, const int* __restrict__ offsets,
    const int* __restrict__ list_token, const float* __restrict__ list_w,
    unsigned short* __restrict__ h)
{
    const int e  = blockIdx.z;
    const int n  = count[e];
    const int m0 = blockIdx.y * GU_M;
    if (m0 >= n) return;
    const int f0 = blockIdx.x * GU_F;
    const int mc = min(GU_M, n - m0);

    __shared__ char  lds[32768];
    __shared__ int   toks[GU_M];
    __shared__ float rws[GU_M];

    const int tid = threadIdx.x;
    if (tid < GU_M) {
        const int idx = e * BS + m0 + (tid < mc ? tid : 0);
        toks[tid] = list_token[idx];
        rws[tid]  = (tid < mc) ? list_w[idx] : 0.f;
    }

    const int lane = tid & 63;
    const int wave = tid >> 6;
    const int wr   = wave >> 1;        // token half (64)
    const int wc   = wave & 1;         // f half (32)
    const int c4   = (tid & 15) * 4;   // staging cols (4 floats)
    const int rr   = tid >> 4;         // staging row base 0..15

    const float* wg = w_gate + (size_t)e * NF * DIM;
    const float* wu = w_up   + (size_t)e * NF * DIM;

    f32x4 accg[4][2] = {};
    f32x4 accu[4][2] = {};

    for (int d0 = 0; d0 < DIM; d0 += GU_BK) {
        __syncthreads();
        // X tile: 128 rows x 64 cols (fp32 -> bf16, swizzled)
        #pragma unroll
        for (int i = 0; i < 8; ++i) {
            const int r = rr + i * 16;
            const float4 v = *(const float4*)&x[(size_t)toks[r] * DIM + d0 + c4];
            *(uint2*)&lds[XOFF + SWZ(r, c4 * 2)] = make_uint2(pack2(v.x, v.y), pack2(v.z, v.w));
        }
        // G,U tiles: 64 rows x 64 cols each
        #pragma unroll
        for (int i = 0; i < 8; ++i) {
            const int r = rr + (i & 3) * 16;
            const float* src = (i < 4 ? wg : wu) + (size_t)(f0 + r) * DIM + d0 + c4;
            const float4 v = *(const float4*)src;
            const int off = (i < 4 ? GOFF : UOFF) + SWZ(r, c4 * 2);
            *(uint2*)&lds[off] = make_uint2(pack2(v.x, v.y), pack2(v.z, v.w));
        }
        __syncthreads();
        #pragma unroll
        for (int ks = 0; ks < 2; ++ks) {
            const int kb = (ks * 32 + (lane >> 4) * 8) * 2;   // byte within row
            bf16x8 a[4], bg[2], bu[2];
            #pragma unroll
            for (int m = 0; m < 4; ++m) {
                const int r = wr * 64 + m * 16 + (lane & 15);
                a[m] = *(const bf16x8*)&lds[XOFF + SWZ(r, kb)];
            }
            #pragma unroll
            for (int nn = 0; nn < 2; ++nn) {
                const int r = wc * 32 + nn * 16 + (lane & 15);
                bg[nn] = *(const bf16x8*)&lds[GOFF + SWZ(r, kb)];
                bu[nn] = *(const bf16x8*)&lds[UOFF + SWZ(r, kb)];
            }
            #pragma unroll
            for (int m = 0; m < 4; ++m)
                #pragma unroll
                for (int nn = 0; nn < 2; ++nn) {
                    accg[m][nn] = __builtin_amdgcn_mfma_f32_16x16x32_bf16(a[m], bg[nn], accg[m][nn], 0, 0, 0);
                    accu[m][nn] = __builtin_amdgcn_mfma_f32_16x16x32_bf16(a[m], bu[nn], accu[m][nn], 0, 0, 0);
                }
        }
    }

    const int base = offsets[e] + m0;
    #pragma unroll
    for (int m = 0; m < 4; ++m) {
        #pragma unroll
        for (int j = 0; j < 4; ++j) {
            const int tl = wr * 64 + m * 16 + (lane >> 4) * 4 + j;
            if (tl < mc) {
                const float w = rws[tl];
                #pragma unroll
                for (int nn = 0; nn < 2; ++nn) {
                    const int fl = f0 + wc * 32 + nn * 16 + (lane & 15);
                    const float g  = accg[m][nn][j];
                    const float u  = accu[m][nn][j];
                    const float hv = w * u * (g / (1.f + __expf(-g)));
                    h[(size_t)(base + tl) * NF + fl] = (unsigned short)f2bf(hv);
                }
            }
        }
    }
}

// ---------------- down MFMA GEMM + atomic combine ----------------
// block: 128 slots x 128 d, K-tile 64 over F=512. 4 waves; wave = 64x64 (4x4).
#define DK_M 128
#define DK_N 128
#define DK_BK 64
#define HOFF 0
#define WOFF (128 * 128)   // 16 KB

__global__ __launch_bounds__(256, 3) void down_mfma(
    const float* __restrict__ w_down,
    const int* __restrict__ count, const int* __restrict__ offsets,
    const int* __restrict__ list_token,
    const unsigned short* __restrict__ h, float* __restrict__ out)
{
    const int e  = blockIdx.z;
    const int n  = count[e];
    const int m0 = blockIdx.y * DK_M;
    if (m0 >= n) return;
    const int d0 = blockIdx.x * DK_N;
    const int mc = min(DK_M, n - m0);

    __shared__ char lds[32768];
    __shared__ int  toks[DK_M];

    const int tid = threadIdx.x;
    if (tid < DK_M) toks[tid] = list_token[e * BS + m0 + (tid < mc ? tid : 0)];

    const int lane = tid & 63;
    const int wave = tid >> 6;
    const int wr  = wave >> 1, wc = wave & 1;
    const int c4  = (tid & 15) * 4;
    const int rr  = tid >> 4;
    const int c8  = (tid & 7) * 8;    // 8 bf16 = 16 B
    const int rr2 = tid >> 3;         // 0..31

    const float* wd  = w_down + (size_t)e * DIM * NF;
    const int   base = offsets[e] + m0;

    f32x4 acc[4][4] = {};

    for (int fs = 0; fs < NF; fs += DK_BK) {
        __syncthreads();
        // H tile: 128 rows x 64 f (already bf16)
        #pragma unroll
        for (int i = 0; i < 4; ++i) {
            const int r  = rr2 + i * 32;
            const int rs = (r < mc ? r : 0);
            const uint4 v = *(const uint4*)&h[(size_t)(base + rs) * NF + fs + c8];
            *(uint4*)&lds[HOFF + SWZ(r, c8 * 2)] = v;
        }
        // W tile: 128 d-rows x 64 f (fp32 -> bf16)
        #pragma unroll
        for (int i = 0; i < 8; ++i) {
            const int r = rr + i * 16;
            const float4 v = *(const float4*)&wd[(size_t)(d0 + r) * NF + fs + c4];
            *(uint2*)&lds[WOFF + SWZ(r, c4 * 2)] = make_uint2(pack2(v.x, v.y), pack2(v.z, v.w));
        }
        __syncthreads();
        #pragma unroll
        for (int ks = 0; ks < 2; ++ks) {
            const int kb = (ks * 32 + (lane >> 4) * 8) * 2;
            bf16x8 a[4], b[4];
            #pragma unroll
            for (int m = 0; m < 4; ++m)
                a[m] = *(const bf16x8*)&lds[HOFF + SWZ(wr * 64 + m * 16 + (lane & 15), kb)];
            #pragma unroll
            for (int nn = 0; nn < 4; ++nn)
                b[nn] = *(const bf16x8*)&lds[WOFF + SWZ(wc * 64 + nn * 16 + (lane & 15), kb)];
            #pragma unroll
            for (int m = 0; m < 4; ++m)
                #pragma unroll
                for (int nn = 0; nn < 4; ++nn)
                    acc[m][nn] = __builtin_amdgcn_mfma_f32_16x16x32_bf16(a[m], b[nn], acc[m][nn], 0, 0, 0);
        }
    }

    #pragma unroll
    for (int m = 0; m < 4; ++m)
        #pragma unroll
        for (int j = 0; j < 4; ++j) {
            const int sl = wr * 64 + m * 16 + (lane >> 4) * 4 + j;
            if (sl < mc) {
                float* orow = out + (size_t)toks[sl] * DIM + d0 + wc * 64 + (lane & 15);
                #pragma unroll
                for (int nn = 0; nn < 4; ++nn)
                    atomicAdd(&orow[nn * 16], acc[m][nn][j]);
            }
        }
}

extern "C" void kernel_launch(void* const* d_in, const int* in_sizes, int n_in,
                              void* d_out, int out_size, void* d_ws, size_t ws_size,
                              hipStream_t stream)
{
    const float* x          = (const float*)d_in[0];
    const float* gate_w     = (const float*)d_in[1];
    const float* w_gate     = (const float*)d_in[2];
    const float* w_up       = (const float*)d_in[3];
    const float* w_down     = (const float*)d_in[4];
    const int*   token_mod  = (const int*)d_in[5];
    const int*   expert_mod = (const int*)d_in[6];
    float* out = (float*)d_out;

    // ws layout: h bf16 (16384*512*2 = 16,777,216 B) | count | offsets | list_token | list_w
    char* ws = (char*)d_ws;
    unsigned short* h  = (unsigned short*)ws;
    int*   count      = (int*)(ws + 16777216);
    int*   offsets    = (int*)(ws + 16777216 + 256);
    int*   list_token = (int*)(ws + 16777216 + 512);
    float* list_w     = (float*)(ws + 16777216 + 512 + (size_t)NE * BS * 4);

    zero_kernel<<<2048, 256, 0, stream>>>(out, count);
    router_kernel<<<BS, 256, 0, stream>>>(x, gate_w, token_mod, expert_mod,
                                          count, list_token, list_w);
    scan_kernel<<<1, 64, 0, stream>>>(count, offsets);

    dim3 g1(NF / GU_F, BS / GU_M, NE);    // (8, 16, 64)
    gateup_mfma<<<g1, 256, 0, stream>>>(x, w_gate, w_up, count, offsets,
                                        list_token, list_w, h);
    dim3 g2(DIM / DK_N, BS / DK_M, NE);   // (16, 16, 64)
    down_mfma<<<g2, 256, 0, stream>>>(w_down, count, offsets, list_token, h, out);
}

// Round 3
// 557.873 us; speedup vs baseline: 5.0950x; 2.3888x over previous
//
#include <hip/hip_runtime.h>
#include <hip/hip_bf16.h>
#include <math.h>

#define BS   2048
#define DIM  2048
#define NE   64
#define NF   512
#define TOPK 8

typedef __attribute__((ext_vector_type(8))) short bf16x8;
typedef __attribute__((ext_vector_type(4))) float f32x4;

// pack 2 f32 -> 2 bf16 (RNE), lo in [15:0]
__device__ __forceinline__ unsigned cvt2(float lo, float hi) {
    unsigned r;
    asm("v_cvt_pk_bf16_f32 %0, %1, %2" : "=v"(r) : "v"(lo), "v"(hi));
    return r;
}
__device__ __forceinline__ unsigned short f2bf(float f) {
    unsigned r = cvt2(f, 0.f);
    return (unsigned short)(r & 0xFFFF);
}

// swizzled LDS addressing: 64-col bf16 rows (128 B), XOR bits 4-6 with row&7
#define SWZ(r, b) (((((r) << 7) + (b)) ^ (((r) & 7) << 4)))

// ---------------- zero out + counters ----------------
__global__ __launch_bounds__(256) void zero_kernel(float* __restrict__ out, int* __restrict__ count)
{
    const size_t idx = (size_t)blockIdx.x * blockDim.x + threadIdx.x;
    const size_t tot = (size_t)BS * DIM;
    for (size_t i = idx * 4; i < tot; i += (size_t)gridDim.x * blockDim.x * 4) {
        *(float4*)&out[i] = make_float4(0.f, 0.f, 0.f, 0.f);
    }
    if (idx < NE) count[idx] = 0;
}

// ---------------- router: 4 tokens/block, wave-parallel top-8 ----------------
__global__ __launch_bounds__(256) void router_kernel(
    const float* __restrict__ x, const float* __restrict__ gate_w,
    const int* __restrict__ token_mod, const int* __restrict__ expert_mod,
    int* __restrict__ count, int* __restrict__ list_token, float* __restrict__ list_w)
{
    __shared__ float xs[4 * DIM];
    __shared__ float pr[4][NE];
    const int t0  = blockIdx.x * 4;
    const int tid = threadIdx.x;
    const int lane = tid & 63, wave = tid >> 6;

    float4* xs4 = (float4*)xs;
    const float4* xr = (const float4*)(x + (size_t)t0 * DIM);
    for (int i = tid; i < 4 * (DIM / 4); i += 256) xs4[i] = xr[i];
    __syncthreads();

    // logits: wave handles 16 experts, all 4 tokens at once
    for (int j = 0; j < 16; ++j) {
        const int e = wave * 16 + j;
        const float4* gw = (const float4*)(gate_w + (size_t)e * DIM);
        float s0 = 0.f, s1 = 0.f, s2 = 0.f, s3 = 0.f;
        for (int i = lane; i < DIM / 4; i += 64) {
            const float4 g  = gw[i];
            const float4 v0 = xs4[0 * 512 + i];
            const float4 v1 = xs4[1 * 512 + i];
            const float4 v2 = xs4[2 * 512 + i];
            const float4 v3 = xs4[3 * 512 + i];
            s0 += v0.x * g.x + v0.y * g.y + v0.z * g.z + v0.w * g.w;
            s1 += v1.x * g.x + v1.y * g.y + v1.z * g.z + v1.w * g.w;
            s2 += v2.x * g.x + v2.y * g.y + v2.z * g.z + v2.w * g.w;
            s3 += v3.x * g.x + v3.y * g.y + v3.z * g.z + v3.w * g.w;
        }
        #pragma unroll
        for (int off = 32; off > 0; off >>= 1) {
            s0 += __shfl_xor(s0, off, 64);
            s1 += __shfl_xor(s1, off, 64);
            s2 += __shfl_xor(s2, off, 64);
            s3 += __shfl_xor(s3, off, 64);
        }
        if (lane == 0) {
            pr[0][e] = s0; pr[1][e] = s1; pr[2][e] = s2; pr[3][e] = s3;
        }
    }
    __syncthreads();

    // wave w: top-8 for token t0+w; lane e owns expert e
    {
        const int t  = t0 + wave;
        const int tm = token_mod[t];
        const int em = expert_mod[lane];
        float p = pr[wave][lane];
        if (tm * em == -1) p = -INFINITY;
        float m0 = p;
        #pragma unroll
        for (int off = 32; off > 0; off >>= 1) m0 = fmaxf(m0, __shfl_xor(m0, off, 64));
        p = __expf(p - m0);                  // exp(-inf)=0; softmax denom cancels in renorm
        float s8 = 0.f, wsel = 0.f;
        int   esel = 0;
        #pragma unroll
        for (int k = 0; k < TOPK; ++k) {
            float m = p;
            #pragma unroll
            for (int off = 32; off > 0; off >>= 1) m = fmaxf(m, __shfl_xor(m, off, 64));
            const unsigned long long b = __ballot(p == m);
            const int bi = __ffsll((unsigned long long)b) - 1;   // lowest index on ties
            if (lane == bi) p = -1.f;
            if (lane == k) { esel = bi; wsel = m; }
            s8 += m;
        }
        const float inv = 1.f / s8;
        if (lane < TOPK) {
            const int pos = atomicAdd(&count[esel], 1);
            list_token[esel * BS + pos] = t;
            list_w[esel * BS + pos]     = wsel * inv;
        }
    }
}

// ---------------- tiny exclusive scan over 64 counts ----------------
__global__ void scan_kernel(const int* __restrict__ count, int* __restrict__ offsets)
{
    if (threadIdx.x == 0) {
        int s = 0;
        for (int e = 0; e < NE; ++e) { offsets[e] = s; s += count[e]; }
    }
}

// ---------------- gate/up MFMA GEMM (reg-staged pipeline) -> h (bf16) ----------------
// block: 128 tokens x 64 f, BK=64, 32 K-steps. 4 waves; wave = 64 tok x 32 f (gate+up).
#define GU_M   128
#define GU_BUF 32768
#define GU_X   0
#define GU_G   16384
#define GU_U   24576

#define GU_COMPUTE(BASE)                                                              \
    {                                                                                 \
        _Pragma("unroll")                                                             \
        for (int ks = 0; ks < 2; ++ks) {                                              \
            const int kb = (ks * 32 + (lane >> 4) * 8) * 2;                           \
            bf16x8 a[4], bg[2], bu[2];                                                \
            _Pragma("unroll")                                                         \
            for (int m = 0; m < 4; ++m)                                               \
                a[m] = *(const bf16x8*)&lds[(BASE) + GU_X + SWZ(wr * 64 + m * 16 + (lane & 15), kb)]; \
            _Pragma("unroll")                                                         \
            for (int nn = 0; nn < 2; ++nn) {                                          \
                const int r = wc * 32 + nn * 16 + (lane & 15);                        \
                bg[nn] = *(const bf16x8*)&lds[(BASE) + GU_G + SWZ(r, kb)];            \
                bu[nn] = *(const bf16x8*)&lds[(BASE) + GU_U + SWZ(r, kb)];            \
            }                                                                         \
            _Pragma("unroll")                                                         \
            for (int m = 0; m < 4; ++m)                                               \
                _Pragma("unroll")                                                     \
                for (int nn = 0; nn < 2; ++nn) {                                      \
                    accg[m][nn] = __builtin_amdgcn_mfma_f32_16x16x32_bf16(a[m], bg[nn], accg[m][nn], 0, 0, 0); \
                    accu[m][nn] = __builtin_amdgcn_mfma_f32_16x16x32_bf16(a[m], bu[nn], accu[m][nn], 0, 0, 0); \
                }                                                                     \
        }                                                                             \
    }

__global__ __launch_bounds__(256, 2) void gateup_mfma(
    const float* __restrict__ x,
    const float* __restrict__ w_gate, const float* __restrict__ w_up,
    const int* __restrict__ count, const int* __restrict__ offsets,
    const int* __restrict__ list_token, const float* __restrict__ list_w,
    unsigned short* __restrict__ h)
{
    const int e  = blockIdx.z;
    const int n  = count[e];
    const int m0 = blockIdx.y * GU_M;
    if (m0 >= n) return;
    const int f0 = blockIdx.x * 64;
    const int mc = min(GU_M, n - m0);

    __shared__ char  lds[2 * GU_BUF];
    __shared__ int   toks[GU_M];
    __shared__ float rws[GU_M];

    const int tid = threadIdx.x;
    if (tid < GU_M) {
        const int idx = e * BS + m0 + (tid < mc ? tid : 0);
        toks[tid] = list_token[idx];
        rws[tid]  = (tid < mc) ? list_w[idx] : 0.f;
    }
    __syncthreads();

    const int lane = tid & 63, wave = tid >> 6;
    const int wr = wave >> 1, wc = wave & 1;
    const int rr = tid >> 4;          // 0..15 staging row base
    const int c4 = (tid & 15) * 4;    // staging float col

    // hoisted row pointers
    const float* xrow[8];
    #pragma unroll
    for (int i = 0; i < 8; ++i) xrow[i] = x + (size_t)toks[rr + i * 16] * DIM + c4;
    const float* grow[4];
    const float* urow[4];
    #pragma unroll
    for (int i = 0; i < 4; ++i) {
        grow[i] = w_gate + (size_t)e * NF * DIM + (size_t)(f0 + rr + i * 16) * DIM + c4;
        urow[i] = w_up   + (size_t)e * NF * DIM + (size_t)(f0 + rr + i * 16) * DIM + c4;
    }

    f32x4 accg[4][2] = {};
    f32x4 accu[4][2] = {};
    float4 lx[8], lg[4], lu[4];

    // prologue: stage step 0 into buf0
    #pragma unroll
    for (int i = 0; i < 8; ++i) lx[i] = *(const float4*)(xrow[i]);
    #pragma unroll
    for (int i = 0; i < 4; ++i) { lg[i] = *(const float4*)(grow[i]); lu[i] = *(const float4*)(urow[i]); }
    #pragma unroll
    for (int i = 0; i < 8; ++i)
        *(uint2*)&lds[GU_X + SWZ(rr + i * 16, c4 * 2)] = make_uint2(cvt2(lx[i].x, lx[i].y), cvt2(lx[i].z, lx[i].w));
    #pragma unroll
    for (int i = 0; i < 4; ++i) {
        *(uint2*)&lds[GU_G + SWZ(rr + i * 16, c4 * 2)] = make_uint2(cvt2(lg[i].x, lg[i].y), cvt2(lg[i].z, lg[i].w));
        *(uint2*)&lds[GU_U + SWZ(rr + i * 16, c4 * 2)] = make_uint2(cvt2(lu[i].x, lu[i].y), cvt2(lu[i].z, lu[i].w));
    }
    __syncthreads();

    for (int t = 0; t < DIM / 64 - 1; ++t) {
        const int cur = (t & 1) * GU_BUF;
        const int nxt = ((t + 1) & 1) * GU_BUF;
        const int doff = (t + 1) * 64;
        // issue next-step loads (kept in flight across compute)
        #pragma unroll
        for (int i = 0; i < 8; ++i) lx[i] = *(const float4*)(xrow[i] + doff);
        #pragma unroll
        for (int i = 0; i < 4; ++i) { lg[i] = *(const float4*)(grow[i] + doff); lu[i] = *(const float4*)(urow[i] + doff); }
        // compute current step
        GU_COMPUTE(cur);
        // convert + write next buffer
        #pragma unroll
        for (int i = 0; i < 8; ++i)
            *(uint2*)&lds[nxt + GU_X + SWZ(rr + i * 16, c4 * 2)] = make_uint2(cvt2(lx[i].x, lx[i].y), cvt2(lx[i].z, lx[i].w));
        #pragma unroll
        for (int i = 0; i < 4; ++i) {
            *(uint2*)&lds[nxt + GU_G + SWZ(rr + i * 16, c4 * 2)] = make_uint2(cvt2(lg[i].x, lg[i].y), cvt2(lg[i].z, lg[i].w));
            *(uint2*)&lds[nxt + GU_U + SWZ(rr + i * 16, c4 * 2)] = make_uint2(cvt2(lu[i].x, lu[i].y), cvt2(lu[i].z, lu[i].w));
        }
        __syncthreads();
    }
    GU_COMPUTE(((DIM / 64 - 1) & 1) * GU_BUF);

    const int base = offsets[e] + m0;
    #pragma unroll
    for (int m = 0; m < 4; ++m) {
        #pragma unroll
        for (int j = 0; j < 4; ++j) {
            const int tl = wr * 64 + m * 16 + (lane >> 4) * 4 + j;
            if (tl < mc) {
                const float w = rws[tl];
                #pragma unroll
                for (int nn = 0; nn < 2; ++nn) {
                    const int fl = f0 + wc * 32 + nn * 16 + (lane & 15);
                    const float g  = accg[m][nn][j];
                    const float u  = accu[m][nn][j];
                    const float hv = w * u * (g / (1.f + __expf(-g)));
                    h[(size_t)(base + tl) * NF + fl] = f2bf(hv);
                }
            }
        }
    }
}

// ---------------- down MFMA GEMM (reg-staged pipeline) + atomic combine ----------------
// block: 128 slots x 128 d, BK=64 over F=512 (8 steps). 4 waves; wave = 64x64.
#define DK_M   128
#define DK_BUF 32768
#define DK_H   0
#define DK_W   16384

#define DK_COMPUTE(BASE)                                                              \
    {                                                                                 \
        _Pragma("unroll")                                                             \
        for (int ks = 0; ks < 2; ++ks) {                                              \
            const int kb = (ks * 32 + (lane >> 4) * 8) * 2;                           \
            bf16x8 a[4], b[4];                                                        \
            _Pragma("unroll")                                                         \
            for (int m = 0; m < 4; ++m)                                               \
                a[m] = *(const bf16x8*)&lds[(BASE) + DK_H + SWZ(wr * 64 + m * 16 + (lane & 15), kb)]; \
            _Pragma("unroll")                                                         \
            for (int nn = 0; nn < 4; ++nn)                                            \
                b[nn] = *(const bf16x8*)&lds[(BASE) + DK_W + SWZ(wc * 64 + nn * 16 + (lane & 15), kb)]; \
            _Pragma("unroll")                                                         \
            for (int m = 0; m < 4; ++m)                                               \
                _Pragma("unroll")                                                     \
                for (int nn = 0; nn < 4; ++nn)                                        \
                    acc[m][nn] = __builtin_amdgcn_mfma_f32_16x16x32_bf16(a[m], b[nn], acc[m][nn], 0, 0, 0); \
        }                                                                             \
    }

__global__ __launch_bounds__(256, 2) void down_mfma(
    const float* __restrict__ w_down,
    const int* __restrict__ count, const int* __restrict__ offsets,
    const int* __restrict__ list_token,
    const unsigned short* __restrict__ h, float* __restrict__ out)
{
    const int e  = blockIdx.z;
    const int n  = count[e];
    const int m0 = blockIdx.y * DK_M;
    if (m0 >= n) return;
    const int d0 = blockIdx.x * 128;
    const int mc = min(DK_M, n - m0);

    __shared__ char lds[2 * DK_BUF];
    __shared__ int  toks[DK_M];

    const int tid = threadIdx.x;
    if (tid < DK_M) toks[tid] = list_token[e * BS + m0 + (tid < mc ? tid : 0)];
    __syncthreads();

    const int lane = tid & 63, wave = tid >> 6;
    const int wr = wave >> 1, wc = wave & 1;
    const int rr = tid >> 4;
    const int c4 = (tid & 15) * 4;
    const int hr = tid >> 3;          // 0..31
    const int hc = (tid & 7) * 8;     // bf16 col (8 per 16B)

    const float* wd  = w_down + (size_t)e * DIM * NF;
    const int   base = offsets[e] + m0;

    // hoisted row pointers
    const unsigned short* hrow[4];
    #pragma unroll
    for (int i = 0; i < 4; ++i) {
        const int r  = hr + i * 32;
        const int rs = (r < mc ? r : 0);
        hrow[i] = h + (size_t)(base + rs) * NF + hc;
    }
    const float* wrow[8];
    #pragma unroll
    for (int i = 0; i < 8; ++i) wrow[i] = wd + (size_t)(d0 + rr + i * 16) * NF + c4;

    f32x4 acc[4][4] = {};
    uint4  lh[4];
    float4 lw[8];

    // prologue: stage step 0
    #pragma unroll
    for (int i = 0; i < 4; ++i) lh[i] = *(const uint4*)(hrow[i]);
    #pragma unroll
    for (int i = 0; i < 8; ++i) lw[i] = *(const float4*)(wrow[i]);
    #pragma unroll
    for (int i = 0; i < 4; ++i)
        *(uint4*)&lds[DK_H + SWZ(hr + i * 32, hc * 2)] = lh[i];
    #pragma unroll
    for (int i = 0; i < 8; ++i)
        *(uint2*)&lds[DK_W + SWZ(rr + i * 16, c4 * 2)] = make_uint2(cvt2(lw[i].x, lw[i].y), cvt2(lw[i].z, lw[i].w));
    __syncthreads();

    for (int t = 0; t < NF / 64 - 1; ++t) {
        const int cur = (t & 1) * DK_BUF;
        const int nxt = ((t + 1) & 1) * DK_BUF;
        const int foff = (t + 1) * 64;
        #pragma unroll
        for (int i = 0; i < 4; ++i) lh[i] = *(const uint4*)(hrow[i] + foff);
        #pragma unroll
        for (int i = 0; i < 8; ++i) lw[i] = *(const float4*)(wrow[i] + foff);
        DK_COMPUTE(cur);
        #pragma unroll
        for (int i = 0; i < 4; ++i)
            *(uint4*)&lds[nxt + DK_H + SWZ(hr + i * 32, hc * 2)] = lh[i];
        #pragma unroll
        for (int i = 0; i < 8; ++i)
            *(uint2*)&lds[nxt + DK_W + SWZ(rr + i * 16, c4 * 2)] = make_uint2(cvt2(lw[i].x, lw[i].y), cvt2(lw[i].z, lw[i].w));
        __syncthreads();
    }
    DK_COMPUTE(((NF / 64 - 1) & 1) * DK_BUF);

    #pragma unroll
    for (int m = 0; m < 4; ++m)
        #pragma unroll
        for (int j = 0; j < 4; ++j) {
            const int sl = wr * 64 + m * 16 + (lane >> 4) * 4 + j;
            if (sl < mc) {
                float* orow = out + (size_t)toks[sl] * DIM + d0 + wc * 64 + (lane & 15);
                #pragma unroll
                for (int nn = 0; nn < 4; ++nn)
                    atomicAdd(&orow[nn * 16], acc[m][nn][j]);
            }
        }
}

extern "C" void kernel_launch(void* const* d_in, const int* in_sizes, int n_in,
                              void* d_out, int out_size, void* d_ws, size_t ws_size,
                              hipStream_t stream)
{
    const float* x          = (const float*)d_in[0];
    const float* gate_w     = (const float*)d_in[1];
    const float* w_gate     = (const float*)d_in[2];
    const float* w_up       = (const float*)d_in[3];
    const float* w_down     = (const float*)d_in[4];
    const int*   token_mod  = (const int*)d_in[5];
    const int*   expert_mod = (const int*)d_in[6];
    float* out = (float*)d_out;

    // ws layout: h bf16 (16384*512*2 = 16,777,216 B) | count | offsets | list_token | list_w
    char* ws = (char*)d_ws;
    unsigned short* h  = (unsigned short*)ws;
    int*   count      = (int*)(ws + 16777216);
    int*   offsets    = (int*)(ws + 16777216 + 256);
    int*   list_token = (int*)(ws + 16777216 + 512);
    float* list_w     = (float*)(ws + 16777216 + 512 + (size_t)NE * BS * 4);

    zero_kernel<<<2048, 256, 0, stream>>>(out, count);
    router_kernel<<<BS / 4, 256, 0, stream>>>(x, gate_w, token_mod, expert_mod,
                                              count, list_token, list_w);
    scan_kernel<<<1, 64, 0, stream>>>(count, offsets);

    dim3 g1(NF / 64, BS / GU_M, NE);    // (8, 16, 64)
    gateup_mfma<<<g1, 256, 0, stream>>>(x, w_gate, w_up, count, offsets,
                                        list_token, list_w, h);
    dim3 g2(DIM / 128, BS / DK_M, NE);  // (16, 16, 64)
    down_mfma<<<g2, 256, 0, stream>>>(w_down, count, offsets, list_token, h, out);
}

// Round 4
// 540.084 us; speedup vs baseline: 5.2628x; 1.0329x over previous
//
#include <hip/hip_runtime.h>
#include <math.h>

#define BS   2048
#define DIM  2048
#define NE   64
#define NF   512
#define TOPK 8

typedef __attribute__((ext_vector_type(8))) short bf16x8;
typedef __attribute__((ext_vector_type(4))) float f32x4;

// pack 2 f32 -> 2 bf16 (RNE), lo in [15:0]
__device__ __forceinline__ unsigned cvt2(float lo, float hi) {
    unsigned r;
    asm("v_cvt_pk_bf16_f32 %0, %1, %2" : "=v"(r) : "v"(lo), "v"(hi));
    return r;
}
__device__ __forceinline__ unsigned short f2bf(float f) {
    unsigned r = cvt2(f, 0.f);
    return (unsigned short)(r & 0xFFFF);
}

// swizzled LDS addressing: 64-col bf16 rows (128 B), XOR bits 4-6 with row&7
#define SWZ(r, b) (((((r) << 7) + (b)) ^ (((r) & 7) << 4)))

// ---------------- zero out + counters ----------------
__global__ __launch_bounds__(256) void zero_kernel(float* __restrict__ out, int* __restrict__ count)
{
    const size_t idx = (size_t)blockIdx.x * blockDim.x + threadIdx.x;
    const size_t tot = (size_t)BS * DIM;
    for (size_t i = idx * 4; i < tot; i += (size_t)gridDim.x * blockDim.x * 4) {
        *(float4*)&out[i] = make_float4(0.f, 0.f, 0.f, 0.f);
    }
    if (idx < NE) count[idx] = 0;
}

// ---------------- router: 4 tokens/block, wave-parallel top-8 ----------------
__global__ __launch_bounds__(256) void router_kernel(
    const float* __restrict__ x, const float* __restrict__ gate_w,
    const int* __restrict__ token_mod, const int* __restrict__ expert_mod,
    int* __restrict__ count, int* __restrict__ list_token, float* __restrict__ list_w)
{
    __shared__ float xs[4 * DIM];
    __shared__ float pr[4][NE];
    const int t0  = blockIdx.x * 4;
    const int tid = threadIdx.x;
    const int lane = tid & 63, wave = tid >> 6;

    float4* xs4 = (float4*)xs;
    const float4* xr = (const float4*)(x + (size_t)t0 * DIM);
    for (int i = tid; i < 4 * (DIM / 4); i += 256) xs4[i] = xr[i];
    __syncthreads();

    for (int j = 0; j < 16; ++j) {
        const int e = wave * 16 + j;
        const float4* gw = (const float4*)(gate_w + (size_t)e * DIM);
        float s0 = 0.f, s1 = 0.f, s2 = 0.f, s3 = 0.f;
        for (int i = lane; i < DIM / 4; i += 64) {
            const float4 g  = gw[i];
            const float4 v0 = xs4[0 * 512 + i];
            const float4 v1 = xs4[1 * 512 + i];
            const float4 v2 = xs4[2 * 512 + i];
            const float4 v3 = xs4[3 * 512 + i];
            s0 += v0.x * g.x + v0.y * g.y + v0.z * g.z + v0.w * g.w;
            s1 += v1.x * g.x + v1.y * g.y + v1.z * g.z + v1.w * g.w;
            s2 += v2.x * g.x + v2.y * g.y + v2.z * g.z + v2.w * g.w;
            s3 += v3.x * g.x + v3.y * g.y + v3.z * g.z + v3.w * g.w;
        }
        #pragma unroll
        for (int off = 32; off > 0; off >>= 1) {
            s0 += __shfl_xor(s0, off, 64);
            s1 += __shfl_xor(s1, off, 64);
            s2 += __shfl_xor(s2, off, 64);
            s3 += __shfl_xor(s3, off, 64);
        }
        if (lane == 0) {
            pr[0][e] = s0; pr[1][e] = s1; pr[2][e] = s2; pr[3][e] = s3;
        }
    }
    __syncthreads();

    {
        const int t  = t0 + wave;
        const int tm = token_mod[t];
        const int em = expert_mod[lane];
        float p = pr[wave][lane];
        if (tm * em == -1) p = -INFINITY;
        float m0 = p;
        #pragma unroll
        for (int off = 32; off > 0; off >>= 1) m0 = fmaxf(m0, __shfl_xor(m0, off, 64));
        p = __expf(p - m0);                  // exp(-inf)=0; softmax denom cancels in renorm
        float s8 = 0.f, wsel = 0.f;
        int   esel = 0;
        #pragma unroll
        for (int k = 0; k < TOPK; ++k) {
            float m = p;
            #pragma unroll
            for (int off = 32; off > 0; off >>= 1) m = fmaxf(m, __shfl_xor(m, off, 64));
            const unsigned long long b = __ballot(p == m);
            const int bi = __ffsll((unsigned long long)b) - 1;   // lowest index on ties
            if (lane == bi) p = -1.f;
            if (lane == k) { esel = bi; wsel = m; }
            s8 += m;
        }
        const float inv = 1.f / s8;
        if (lane < TOPK) {
            const int pos = atomicAdd(&count[esel], 1);
            list_token[esel * BS + pos] = t;
            list_w[esel * BS + pos]     = wsel * inv;
        }
    }
}

// ---------------- tiny exclusive scan over 64 counts ----------------
__global__ void scan_kernel(const int* __restrict__ count, int* __restrict__ offsets)
{
    if (threadIdx.x == 0) {
        int s = 0;
        for (int e = 0; e < NE; ++e) { offsets[e] = s; s += count[e]; }
    }
}

// ---------------- gate/up MFMA GEMM (reg-staged pipeline) -> h (bf16) ----------------
// block: 64 tokens x 64 f, BK=64, 32 K-steps. 4 waves; wave = 32 tok x 32 f (gate+up).
// LDS/buf: X 8KB | G 8KB | U 8KB = 24KB; dbuf 48KB -> 3 blocks/CU.
#define GU_BUF 24576
#define GU_X   0
#define GU_G   8192
#define GU_U   16384

#define GU_COMPUTE(BASE)                                                              \
    {                                                                                 \
        _Pragma("unroll")                                                             \
        for (int ks = 0; ks < 2; ++ks) {                                              \
            const int kb = (ks * 32 + (lane >> 4) * 8) * 2;                           \
            bf16x8 a[2], bg[2], bu[2];                                                \
            _Pragma("unroll")                                                         \
            for (int m = 0; m < 2; ++m)                                               \
                a[m] = *(const bf16x8*)&lds[(BASE) + GU_X + SWZ(wr * 32 + m * 16 + (lane & 15), kb)]; \
            _Pragma("unroll")                                                         \
            for (int nn = 0; nn < 2; ++nn) {                                          \
                const int r = wc * 32 + nn * 16 + (lane & 15);                        \
                bg[nn] = *(const bf16x8*)&lds[(BASE) + GU_G + SWZ(r, kb)];            \
                bu[nn] = *(const bf16x8*)&lds[(BASE) + GU_U + SWZ(r, kb)];            \
            }                                                                         \
            _Pragma("unroll")                                                         \
            for (int m = 0; m < 2; ++m)                                               \
                _Pragma("unroll")                                                     \
                for (int nn = 0; nn < 2; ++nn) {                                      \
                    accg[m][nn] = __builtin_amdgcn_mfma_f32_16x16x32_bf16(a[m], bg[nn], accg[m][nn], 0, 0, 0); \
                    accu[m][nn] = __builtin_amdgcn_mfma_f32_16x16x32_bf16(a[m], bu[nn], accu[m][nn], 0, 0, 0); \
                }                                                                     \
        }                                                                             \
    }

__global__ __launch_bounds__(256, 3) void gateup_mfma(
    const float* __restrict__ x,
    const float* __restrict__ w_gate, const float* __restrict__ w_up,
    const int* __restrict__ count, const int* __restrict__ offsets,
    const int* __restrict__ list_token, const float* __restrict__ list_w,
    unsigned short* __restrict__ h)
{
    const int e  = blockIdx.z;
    const int n  = count[e];
    const int m0 = blockIdx.y * 64;
    if (m0 >= n) return;
    const int f0 = blockIdx.x * 64;
    const int mc = min(64, n - m0);

    __shared__ char  lds[2 * GU_BUF];
    __shared__ int   toks[64];
    __shared__ float rws[64];

    const int tid = threadIdx.x;
    if (tid < 64) {
        const int idx = e * BS + m0 + (tid < mc ? tid : 0);
        toks[tid] = list_token[idx];
        rws[tid]  = (tid < mc) ? list_w[idx] : 0.f;
    }
    __syncthreads();

    const int lane = tid & 63, wave = tid >> 6;
    const int wr = wave >> 1, wc = wave & 1;
    const int rr = tid >> 4;          // 0..15 staging row base
    const int c4 = tid & 15;          // float4 col index (16 per row)

    const float* xrow[4];
    #pragma unroll
    for (int i = 0; i < 4; ++i) xrow[i] = x + (size_t)toks[rr + i * 16] * DIM + c4 * 4;
    const float* grow[4];
    const float* urow[4];
    #pragma unroll
    for (int i = 0; i < 4; ++i) {
        grow[i] = w_gate + (size_t)e * NF * DIM + (size_t)(f0 + rr + i * 16) * DIM + c4 * 4;
        urow[i] = w_up   + (size_t)e * NF * DIM + (size_t)(f0 + rr + i * 16) * DIM + c4 * 4;
    }

    f32x4 accg[2][2] = {};
    f32x4 accu[2][2] = {};
    float4 lx[4], lg[4], lu[4];

    // prologue: stage step 0 into buf0
    #pragma unroll
    for (int i = 0; i < 4; ++i) {
        lx[i] = *(const float4*)(xrow[i]);
        lg[i] = *(const float4*)(grow[i]);
        lu[i] = *(const float4*)(urow[i]);
    }
    #pragma unroll
    for (int i = 0; i < 4; ++i) {
        const int r = rr + i * 16;
        *(uint2*)&lds[GU_X + SWZ(r, c4 * 8)] = make_uint2(cvt2(lx[i].x, lx[i].y), cvt2(lx[i].z, lx[i].w));
        *(uint2*)&lds[GU_G + SWZ(r, c4 * 8)] = make_uint2(cvt2(lg[i].x, lg[i].y), cvt2(lg[i].z, lg[i].w));
        *(uint2*)&lds[GU_U + SWZ(r, c4 * 8)] = make_uint2(cvt2(lu[i].x, lu[i].y), cvt2(lu[i].z, lu[i].w));
    }
    __syncthreads();

    for (int t = 0; t < DIM / 64 - 1; ++t) {
        const int cur = (t & 1) * GU_BUF;
        const int nxt = ((t + 1) & 1) * GU_BUF;
        const int doff = (t + 1) * 64;
        #pragma unroll
        for (int i = 0; i < 4; ++i) {
            lx[i] = *(const float4*)(xrow[i] + doff);
            lg[i] = *(const float4*)(grow[i] + doff);
            lu[i] = *(const float4*)(urow[i] + doff);
        }
        GU_COMPUTE(cur);
        #pragma unroll
        for (int i = 0; i < 4; ++i) {
            const int r = rr + i * 16;
            *(uint2*)&lds[nxt + GU_X + SWZ(r, c4 * 8)] = make_uint2(cvt2(lx[i].x, lx[i].y), cvt2(lx[i].z, lx[i].w));
            *(uint2*)&lds[nxt + GU_G + SWZ(r, c4 * 8)] = make_uint2(cvt2(lg[i].x, lg[i].y), cvt2(lg[i].z, lg[i].w));
            *(uint2*)&lds[nxt + GU_U + SWZ(r, c4 * 8)] = make_uint2(cvt2(lu[i].x, lu[i].y), cvt2(lu[i].z, lu[i].w));
        }
        __syncthreads();
    }
    GU_COMPUTE(((DIM / 64 - 1) & 1) * GU_BUF);

    const int base = offsets[e] + m0;
    #pragma unroll
    for (int m = 0; m < 2; ++m) {
        #pragma unroll
        for (int j = 0; j < 4; ++j) {
            const int tl = wr * 32 + m * 16 + (lane >> 4) * 4 + j;
            if (tl < mc) {
                const float w = rws[tl];
                #pragma unroll
                for (int nn = 0; nn < 2; ++nn) {
                    const int fl = f0 + wc * 32 + nn * 16 + (lane & 15);
                    const float g  = accg[m][nn][j];
                    const float u  = accu[m][nn][j];
                    const float hv = w * u * (g / (1.f + __expf(-g)));
                    h[(size_t)(base + tl) * NF + fl] = f2bf(hv);
                }
            }
        }
    }
}

// ---------------- down MFMA GEMM (reg-staged pipeline) + atomic combine ----------------
// block: 64 slots x 128 d, BK=64 over F=512 (8 steps). 4 waves; wave = 32 x 64.
// LDS/buf: H 8KB | W 16KB = 24KB; dbuf 48KB -> 3 blocks/CU.
#define DK_BUF 24576
#define DK_H   0
#define DK_W   8192

#define DK_COMPUTE(BASE)                                                              \
    {                                                                                 \
        _Pragma("unroll")                                                             \
        for (int ks = 0; ks < 2; ++ks) {                                              \
            const int kb = (ks * 32 + (lane >> 4) * 8) * 2;                           \
            bf16x8 a[2], b[4];                                                        \
            _Pragma("unroll")                                                         \
            for (int m = 0; m < 2; ++m)                                               \
                a[m] = *(const bf16x8*)&lds[(BASE) + DK_H + SWZ(wr * 32 + m * 16 + (lane & 15), kb)]; \
            _Pragma("unroll")                                                         \
            for (int nn = 0; nn < 4; ++nn)                                            \
                b[nn] = *(const bf16x8*)&lds[(BASE) + DK_W + SWZ(wc * 64 + nn * 16 + (lane & 15), kb)]; \
            _Pragma("unroll")                                                         \
            for (int m = 0; m < 2; ++m)                                               \
                _Pragma("unroll")                                                     \
                for (int nn = 0; nn < 4; ++nn)                                        \
                    acc[m][nn] = __builtin_amdgcn_mfma_f32_16x16x32_bf16(a[m], b[nn], acc[m][nn], 0, 0, 0); \
        }                                                                             \
    }

__global__ __launch_bounds__(256, 3) void down_mfma(
    const float* __restrict__ w_down,
    const int* __restrict__ count, const int* __restrict__ offsets,
    const int* __restrict__ list_token,
    const unsigned short* __restrict__ h, float* __restrict__ out)
{
    const int e  = blockIdx.z;
    const int n  = count[e];
    const int m0 = blockIdx.y * 64;
    if (m0 >= n) return;
    const int d0 = blockIdx.x * 128;
    const int mc = min(64, n - m0);

    __shared__ char lds[2 * DK_BUF];
    __shared__ int  toks[64];

    const int tid = threadIdx.x;
    if (tid < 64) toks[tid] = list_token[e * BS + m0 + (tid < mc ? tid : 0)];
    __syncthreads();

    const int lane = tid & 63, wave = tid >> 6;
    const int wr = wave >> 1, wc = wave & 1;
    const int rr = tid >> 4;          // 0..15 (W rows)
    const int c4 = tid & 15;          // float4 col
    const int hr = tid >> 3;          // 0..31 (H rows)
    const int hc = (tid & 7) * 8;     // bf16 col (8 per 16B)

    const float* wd  = w_down + (size_t)e * DIM * NF;
    const int   base = offsets[e] + m0;

    const unsigned short* hrow[2];
    #pragma unroll
    for (int i = 0; i < 2; ++i) {
        const int r  = hr + i * 32;
        const int rs = (r < mc ? r : 0);
        hrow[i] = h + (size_t)(base + rs) * NF + hc;
    }
    const float* wrow[8];
    #pragma unroll
    for (int i = 0; i < 8; ++i) wrow[i] = wd + (size_t)(d0 + rr + i * 16) * NF + c4 * 4;

    f32x4 acc[2][4] = {};
    uint4  lh[2];
    float4 lw[8];

    // prologue
    #pragma unroll
    for (int i = 0; i < 2; ++i) lh[i] = *(const uint4*)(hrow[i]);
    #pragma unroll
    for (int i = 0; i < 8; ++i) lw[i] = *(const float4*)(wrow[i]);
    #pragma unroll
    for (int i = 0; i < 2; ++i)
        *(uint4*)&lds[DK_H + SWZ(hr + i * 32, hc * 2)] = lh[i];
    #pragma unroll
    for (int i = 0; i < 8; ++i)
        *(uint2*)&lds[DK_W + SWZ(rr + i * 16, c4 * 8)] = make_uint2(cvt2(lw[i].x, lw[i].y), cvt2(lw[i].z, lw[i].w));
    __syncthreads();

    for (int t = 0; t < NF / 64 - 1; ++t) {
        const int cur = (t & 1) * DK_BUF;
        const int nxt = ((t + 1) & 1) * DK_BUF;
        const int foff = (t + 1) * 64;
        #pragma unroll
        for (int i = 0; i < 2; ++i) lh[i] = *(const uint4*)(hrow[i] + foff);
        #pragma unroll
        for (int i = 0; i < 8; ++i) lw[i] = *(const float4*)(wrow[i] + foff);
        DK_COMPUTE(cur);
        #pragma unroll
        for (int i = 0; i < 2; ++i)
            *(uint4*)&lds[nxt + DK_H + SWZ(hr + i * 32, hc * 2)] = lh[i];
        #pragma unroll
        for (int i = 0; i < 8; ++i)
            *(uint2*)&lds[nxt + DK_W + SWZ(rr + i * 16, c4 * 8)] = make_uint2(cvt2(lw[i].x, lw[i].y), cvt2(lw[i].z, lw[i].w));
        __syncthreads();
    }
    DK_COMPUTE(((NF / 64 - 1) & 1) * DK_BUF);

    #pragma unroll
    for (int m = 0; m < 2; ++m)
        #pragma unroll
        for (int j = 0; j < 4; ++j) {
            const int sl = wr * 32 + m * 16 + (lane >> 4) * 4 + j;
            if (sl < mc) {
                float* orow = out + (size_t)toks[sl] * DIM + d0 + wc * 64 + (lane & 15);
                #pragma unroll
                for (int nn = 0; nn < 4; ++nn)
                    atomicAdd(&orow[nn * 16], acc[m][nn][j]);
            }
        }
}

extern "C" void kernel_launch(void* const* d_in, const int* in_sizes, int n_in,
                              void* d_out, int out_size, void* d_ws, size_t ws_size,
                              hipStream_t stream)
{
    const float* x          = (const float*)d_in[0];
    const float* gate_w     = (const float*)d_in[1];
    const float* w_gate     = (const float*)d_in[2];
    const float* w_up       = (const float*)d_in[3];
    const float* w_down     = (const float*)d_in[4];
    const int*   token_mod  = (const int*)d_in[5];
    const int*   expert_mod = (const int*)d_in[6];
    float* out = (float*)d_out;

    // ws layout: h bf16 (16384*512*2 = 16,777,216 B) | count | offsets | list_token | list_w
    char* ws = (char*)d_ws;
    unsigned short* h  = (unsigned short*)ws;
    int*   count      = (int*)(ws + 16777216);
    int*   offsets    = (int*)(ws + 16777216 + 256);
    int*   list_token = (int*)(ws + 16777216 + 512);
    float* list_w     = (float*)(ws + 16777216 + 512 + (size_t)NE * BS * 4);

    zero_kernel<<<2048, 256, 0, stream>>>(out, count);
    router_kernel<<<BS / 4, 256, 0, stream>>>(x, gate_w, token_mod, expert_mod,
                                              count, list_token, list_w);
    scan_kernel<<<1, 64, 0, stream>>>(count, offsets);

    dim3 g1(NF / 64, BS / 64, NE);     // (8, 32, 64)
    gateup_mfma<<<g1, 256, 0, stream>>>(x, w_gate, w_up, count, offsets,
                                        list_token, list_w, h);
    dim3 g2(DIM / 128, BS / 64, NE);   // (16, 32, 64)
    down_mfma<<<g2, 256, 0, stream>>>(w_down, count, offsets, list_token, h, out);
}